// Round 8
// baseline (356.421 us; speedup 1.0000x reference)
//
#include <hip/hip_runtime.h>
#include <math.h>

#define NIMG 32
#define CDIM 256
#define KCL  64
#define SPIX 4096

// ---------------- K0: transpose conv_w (K x C) -> wT (C x K) ----------------
__global__ __launch_bounds__(256) void k_wt(const float* __restrict__ w, float* __restrict__ wT) {
    int g = blockIdx.x * 256 + threadIdx.x;   // g = k*CDIM + c
    if (g < KCL * CDIM) {
        int k = g / CDIM, c = g % CDIM;
        wT[c * KCL + k] = w[g];
    }
}

// ---------------- K1: fused norm + logits + softmax + asum ------------------
// grid 512 = (n, 16 groups of 256 px), 512 threads = 8 waves; lane = k (64),
// wave wv owns pixels [32wv, 32wv+32). EXACT k_vlad-r5 loop shape with the
// GEMM flipped: per-lane operand = w (LDS b32, 8KB chunk, conflict-free),
// uniform operand = x[n][c][s-slice] (contiguous 8 float4 -> batched s_load,
// NO unroll pragma -- round 7's unroll-8 blew the SGPR budget and demoted the
// s_loads). Norm applied post-loop by linearity; invn from a phase-0 pass.
__global__ __launch_bounds__(512, 4) void k_logits(const float* __restrict__ x,
                                                   const float* __restrict__ wT,
                                                   const float* __restrict__ b,
                                                   float* __restrict__ aT,
                                                   float* __restrict__ inv_norm,
                                                   float* __restrict__ asum_part) {
    int blk = blockIdx.x;
    int n = blk >> 4, g = blk & 15;
    int s0 = g * 256;
    int tid = threadIdx.x;
    int wv = tid >> 6, l = tid & 63;
    int wvu = __builtin_amdgcn_readfirstlane(wv);

    __shared__ float wlds[32 * 64];    // 8 KB w chunk [c-in-chunk][k]
    __shared__ float4 red4[8 * 64];    // 8 KB cross-wave sumsq reduce
    __shared__ float invs[256];        // 1 KB per-pixel inv norm
    __shared__ float reda[8 * 64];     // 2 KB asum reduce

    // ---- phase 0: sumsq over all 256 c for this block's 256 px (coalesced) ----
    float4 sq = {0.f, 0.f, 0.f, 0.f};
    int p4 = l * 4;
    for (int t = 0; t < 8; t++) {
        #pragma unroll
        for (int i = 0; i < 4; i++) {
            int c = t * 32 + wvu + 8 * i;
            float4 xq = *(const float4*)(x + ((size_t)(n * CDIM + c)) * SPIX + s0 + p4);
            sq.x = fmaf(xq.x, xq.x, sq.x);
            sq.y = fmaf(xq.y, xq.y, sq.y);
            sq.z = fmaf(xq.z, xq.z, sq.z);
            sq.w = fmaf(xq.w, xq.w, sq.w);
        }
    }
    red4[wv * 64 + l] = sq;
    __syncthreads();
    if (wv == 0) {
        float4 ssq = red4[l];
        #pragma unroll
        for (int i = 1; i < 8; i++) {
            float4 t4 = red4[i * 64 + l];
            ssq.x += t4.x; ssq.y += t4.y; ssq.z += t4.z; ssq.w += t4.w;
        }
        float4 invn;
        invn.x = 1.f / fmaxf(sqrtf(ssq.x), 1e-12f);
        invn.y = 1.f / fmaxf(sqrtf(ssq.y), 1e-12f);
        invn.z = 1.f / fmaxf(sqrtf(ssq.z), 1e-12f);
        invn.w = 1.f / fmaxf(sqrtf(ssq.w), 1e-12f);
        *(float4*)(invs + 4 * l) = invn;
        *(float4*)(inv_norm + (size_t)n * SPIX + s0 + 4 * l) = invn;
    }

    // ---- phase 1: raw logits, k_vlad-r5 loop shape ----
    float acc[32];
    #pragma unroll
    for (int i = 0; i < 32; i++) acc[i] = 0.f;

    int pbase = 32 * wvu;                                  // wave's pixel base
    const float* xb = x + ((size_t)n * CDIM) * SPIX + s0 + pbase;   // uniform

    for (int t = 0; t < 8; t++) {
        __syncthreads();   // also covers phase-0 invs write on t=0
        ((float4*)wlds)[tid] = ((const float4*)(wT + (size_t)(t * 32) * KCL))[tid];
        __syncthreads();
        for (int cc = 0; cc < 32; cc++) {
            float wl = wlds[cc * 64 + l];                  // per-lane b32, 2-way (free)
            const float4* xp = (const float4*)(xb + (size_t)(t * 32 + cc) * SPIX);
            #pragma unroll
            for (int q = 0; q < 8; q++) {
                float4 x4 = xp[q];                         // uniform -> s_load
                acc[4*q+0] = fmaf(x4.x, wl, acc[4*q+0]);
                acc[4*q+1] = fmaf(x4.y, wl, acc[4*q+1]);
                acc[4*q+2] = fmaf(x4.z, wl, acc[4*q+2]);
                acc[4*q+3] = fmaf(x4.w, wl, acc[4*q+3]);
            }
        }
    }

    // ---- epilogue: scale+bias, softmax over k (= lanes), a-write, asum ----
    float bl = b[l];                                       // per-lane bias
    float asum_l = 0.f;
    float* aout = aT + ((size_t)(n * SPIX + s0 + pbase)) * KCL + l;
    #pragma unroll
    for (int p = 0; p < 32; p++) {
        float lg = fmaf(acc[p], invs[pbase + p], bl);      // uniform ds_read
        float m = lg;
        #pragma unroll
        for (int off = 32; off > 0; off >>= 1) m = fmaxf(m, __shfl_xor(m, off, 64));
        float e = __expf(lg - m);
        float ss = e;
        #pragma unroll
        for (int off = 32; off > 0; off >>= 1) ss += __shfl_xor(ss, off, 64);
        float a = e * (1.f / ss);
        aout[(size_t)p * KCL] = a;                         // 64 lanes: 256B contiguous
        asum_l += a;
    }
    reda[wv * 64 + l] = asum_l;
    __syncthreads();
    if (wv == 0) {
        float t = reda[l];
        #pragma unroll
        for (int i = 1; i < 8; i++) t += reda[i * 64 + l];
        asum_part[blk * KCL + l] = t;
    }
}

// ---------------- K2: vlad partials (round-5 version, verbatim) -------------
// grid 512 = (n, 16 groups of 256 px), 512 threads = (kh = tid>>8, c = tid&255)
// Per-lane x^ from LDS b32 (pad-33, conflict-free), uniform a-slice via
// batched s_load. Hit the fp32 VALU roofline in round 5 -- do not touch.
__global__ __launch_bounds__(512, 4) void k_vlad(const float* __restrict__ x,
                                                 const float* __restrict__ inv_norm,
                                                 const float* __restrict__ aT,
                                                 float* __restrict__ vlad_part) {
    int blk = blockIdx.x;
    int n = blk >> 4, g = blk & 15;
    int tid = threadIdx.x;
    int kh = __builtin_amdgcn_readfirstlane(tid >> 8);   // wave-uniform
    int c = tid & 255;

    __shared__ float xt[256 * 33];   // [c][s32], pad 33: conflict-free per-lane reads

    float acc[32];
    #pragma unroll
    for (int i = 0; i < 32; i++) acc[i] = 0.f;

    int sl = tid & 31;       // staging pixel 0..31
    int cr = tid >> 5;       // staging row 0..15

    for (int t = 0; t < 8; t++) {
        int s0 = g * 256 + t * 32;
        float invp = inv_norm[n * SPIX + s0 + sl];
        __syncthreads();   // previous chunk's reads done before overwrite
        #pragma unroll
        for (int i = 0; i < 16; i++) {
            int cc = cr + i * 16;
            xt[cc * 33 + sl] = x[((size_t)n * CDIM + cc) * SPIX + s0 + sl] * invp;
        }
        __syncthreads();

        const float* ab = aT + ((size_t)(n * SPIX + s0)) * KCL + kh * 32;  // uniform
        for (int ss = 0; ss < 32; ss++) {
            float xn = xt[c * 33 + ss];                       // per-lane, conflict-free
            const float4* ap = (const float4*)(ab + ss * 64); // uniform -> s_load
            #pragma unroll
            for (int q = 0; q < 8; q++) {
                float4 a4 = ap[q];
                acc[4*q+0] = fmaf(a4.x, xn, acc[4*q+0]);
                acc[4*q+1] = fmaf(a4.y, xn, acc[4*q+1]);
                acc[4*q+2] = fmaf(a4.z, xn, acc[4*q+2]);
                acc[4*q+3] = fmaf(a4.w, xn, acc[4*q+3]);
            }
        }
    }
    float* vp = vlad_part + ((size_t)blk * KCL + kh * 32) * CDIM + c;
    #pragma unroll
    for (int i = 0; i < 32; i++) vp[(size_t)i * CDIM] = acc[i];   // coalesced
}

// ---------------- K4: combine partials + centroid subtract + intra-norm ----
// grid 2048 = (n,k), 256 threads (c = tid)
__global__ __launch_bounds__(256) void k_combine(const float* __restrict__ vlad_part,
                                                 const float* __restrict__ asum_part,
                                                 const float* __restrict__ cent,
                                                 float* __restrict__ out,
                                                 float* __restrict__ rs) {
    int blk = blockIdx.x;          // n*64 + k
    int n = blk >> 6, k = blk & 63;
    int c = threadIdx.x;
    float v = 0.f;
    for (int j = 0; j < 16; j++)
        v += vlad_part[(((size_t)(n * 16 + j)) * KCL + k) * CDIM + c];
    float as = 0.f;
    for (int j = 0; j < 16; j++)
        as += asum_part[(n * 16 + j) * KCL + k];
    v = fmaf(-as, cent[k * CDIM + c], v);

    float t = v * v;
    #pragma unroll
    for (int off = 32; off > 0; off >>= 1) t += __shfl_xor(t, off, 64);
    __shared__ float w4[4];
    int lane = threadIdx.x & 63, wid = threadIdx.x >> 6;
    if (lane == 0) w4[wid] = t;
    __syncthreads();
    float ss = w4[0] + w4[1] + w4[2] + w4[3];
    float inv = 1.0f / fmaxf(sqrtf(ss), 1e-12f);
    out[(size_t)blk * CDIM + c] = v * inv;
    if (threadIdx.x == 0) rs[blk] = ss * inv * inv;
}

// ---------------- K5: global L2 normalize per image (in place) --------------
// grid 256 = (n, 8), 256 threads
__global__ __launch_bounds__(256) void k_gnorm(const float* __restrict__ rs,
                                               float* __restrict__ out) {
    int n = blockIdx.x >> 3, j = blockIdx.x & 7;
    float ss = 0.f;
    for (int k = 0; k < KCL; k++) ss += rs[n * KCL + k];
    float g = 1.0f / fmaxf(sqrtf(ss), 1e-12f);
    size_t base = (size_t)n * (KCL * CDIM) + j * 2048 + threadIdx.x;
    for (int i = 0; i < 8; i++) out[base + i * 256] *= g;
}

extern "C" void kernel_launch(void* const* d_in, const int* in_sizes, int n_in,
                              void* d_out, int out_size, void* d_ws, size_t ws_size,
                              hipStream_t stream) {
    const float* x    = (const float*)d_in[0];   // [32][256][64][64]
    const float* w    = (const float*)d_in[1];   // [64][256]
    const float* b    = (const float*)d_in[2];   // [64]
    const float* cent = (const float*)d_in[3];   // [64][256]
    float* out = (float*)d_out;

    float* ws = (float*)d_ws;
    float* wT        = ws;                        // 16384
    float* inv_norm  = wT + 16384;                // 131072
    float* aT        = inv_norm + 131072;         // 32*4096*64 = 8388608
    float* vlad_part = aT + 8388608;              // 512*64*256 = 8388608
    float* asum_part = vlad_part + 8388608;       // 512*64 = 32768
    float* rs        = asum_part + 32768;         // 2048

    k_wt<<<64, 256, 0, stream>>>(w, wT);
    k_logits<<<512, 512, 0, stream>>>(x, wT, b, aT, inv_norm, asum_part);
    k_vlad<<<512, 512, 0, stream>>>(x, inv_norm, aT, vlad_part);
    k_combine<<<2048, 256, 0, stream>>>(vlad_part, asum_part, cent, out, rs);
    k_gnorm<<<256, 256, 0, stream>>>(rs, out);
}

// Round 9
// 184.799 us; speedup vs baseline: 1.9287x; 1.9287x over previous
//
#include <hip/hip_runtime.h>
#include <math.h>

#define NIMG 32
#define CDIM 256
#define KCL  64
#define SPIX 4096

// ---------------- K0: transpose conv_w (K x C) -> wT (C x K) ----------------
__global__ __launch_bounds__(256) void k_wt(const float* __restrict__ w, float* __restrict__ wT) {
    int g = blockIdx.x * 256 + threadIdx.x;   // g = k*CDIM + c
    if (g < KCL * CDIM) {
        int k = g / CDIM, c = g % CDIM;
        wT[c * KCL + k] = w[g];
    }
}

#define WFMA32() \
    acc[0]=fmaf(w0_.x,xv,acc[0]);   acc[1]=fmaf(w0_.y,xv,acc[1]); \
    acc[2]=fmaf(w0_.z,xv,acc[2]);   acc[3]=fmaf(w0_.w,xv,acc[3]); \
    acc[4]=fmaf(w1_.x,xv,acc[4]);   acc[5]=fmaf(w1_.y,xv,acc[5]); \
    acc[6]=fmaf(w1_.z,xv,acc[6]);   acc[7]=fmaf(w1_.w,xv,acc[7]); \
    acc[8]=fmaf(w2_.x,xv,acc[8]);   acc[9]=fmaf(w2_.y,xv,acc[9]); \
    acc[10]=fmaf(w2_.z,xv,acc[10]); acc[11]=fmaf(w2_.w,xv,acc[11]); \
    acc[12]=fmaf(w3_.x,xv,acc[12]); acc[13]=fmaf(w3_.y,xv,acc[13]); \
    acc[14]=fmaf(w3_.z,xv,acc[14]); acc[15]=fmaf(w3_.w,xv,acc[15]); \
    acc[16]=fmaf(w4_.x,xv,acc[16]); acc[17]=fmaf(w4_.y,xv,acc[17]); \
    acc[18]=fmaf(w4_.z,xv,acc[18]); acc[19]=fmaf(w4_.w,xv,acc[19]); \
    acc[20]=fmaf(w5_.x,xv,acc[20]); acc[21]=fmaf(w5_.y,xv,acc[21]); \
    acc[22]=fmaf(w5_.z,xv,acc[22]); acc[23]=fmaf(w5_.w,xv,acc[23]); \
    acc[24]=fmaf(w6_.x,xv,acc[24]); acc[25]=fmaf(w6_.y,xv,acc[25]); \
    acc[26]=fmaf(w6_.z,xv,acc[26]); acc[27]=fmaf(w6_.w,xv,acc[27]); \
    acc[28]=fmaf(w7_.x,xv,acc[28]); acc[29]=fmaf(w7_.y,xv,acc[29]); \
    acc[30]=fmaf(w7_.z,xv,acc[30]); acc[31]=fmaf(w7_.w,xv,acc[31]);

// ---------------- K1: fused norm + logits + softmax + asum ------------------
// grid 512 = (n, 16 groups of 256 px), 512 threads = (khu = tid>>8, sl = tid&255).
// EXACT k_vlad-r5 loop shape: per-lane operand (x) from LDS b32 conflict-free,
// uniform operand (w 32-k slice) = dense-stride s_load stream (128B per 256B
// row, sequential — same density as k_vlad's a-stream), acc[32], and NO outer
// unroll pragma: compiler-chosen unroll/batching (r6/r7's "#pragma unroll 8"
// demanded 256 live uniform SGPRs -> demoted loads; r8's 16KB-stride uniform
// stream thrashed the K$ at SGPR=32 -> 307us).
__global__ __launch_bounds__(512, 4) void k_logits(const float* __restrict__ x,
                                                   const float* __restrict__ wT,
                                                   const float* __restrict__ b,
                                                   float* __restrict__ aT,
                                                   float* __restrict__ inv_norm,
                                                   float* __restrict__ asum_part) {
    int blk = blockIdx.x;
    int n = blk >> 4, g = blk & 15;
    int s0 = g * 256;
    int tid = threadIdx.x;
    int wv = tid >> 6, l = tid & 63;
    int sl = tid & 255;
    int khu = __builtin_amdgcn_readfirstlane(tid >> 8);

    __shared__ float xs[32 * 256];     // [c-in-chunk][px] 32 KB
    __shared__ float4 red4[8 * 64];    // cross-wave sumsq reduce (8 KB)
    __shared__ float redf[512];        // per-pixel softmax reduces (2 KB)
    __shared__ float invs[256];        // per-pixel inv norm (1 KB)

    float acc[32];
    #pragma unroll
    for (int i = 0; i < 32; i++) acc[i] = 0.f;
    float4 sq = {0.f, 0.f, 0.f, 0.f};

    int cst = tid >> 6;            // staging c base (0..7)
    int p4 = (tid & 63) * 4;       // staging pixel quad

    for (int t = 0; t < 8; t++) {
        if (t) __syncthreads();
        #pragma unroll
        for (int i = 0; i < 4; i++) {
            int c = cst + 8 * i;
            float4 xq = *(const float4*)(x + ((size_t)(n * CDIM + t * 32 + c)) * SPIX + s0 + p4);
            sq.x = fmaf(xq.x, xq.x, sq.x);
            sq.y = fmaf(xq.y, xq.y, sq.y);
            sq.z = fmaf(xq.z, xq.z, sq.z);
            sq.w = fmaf(xq.w, xq.w, sq.w);
            *(float4*)(xs + c * 256 + p4) = xq;   // contiguous b128: conflict-free
        }
        __syncthreads();
        const float* wrow = wT + (size_t)(t * 32) * KCL + khu * 32;   // uniform, dense
        for (int cc = 0; cc < 32; cc++) {          // compiler-chosen unroll (like k_vlad)
            float xv = xs[cc * 256 + sl];          // per-lane b32, conflict-free
            const float4* wp = (const float4*)(wrow + (size_t)cc * KCL);
            float4 w0_=wp[0], w1_=wp[1], w2_=wp[2], w3_=wp[3];
            float4 w4_=wp[4], w5_=wp[5], w6_=wp[6], w7_=wp[7];   // batched s_load
            WFMA32()
        }
    }

    // ---- inv norm: cross-wave sumsq reduce (each wave covered 32 of 256 c) ----
    red4[wv * 64 + l] = sq;
    __syncthreads();
    if (wv == 0) {
        float4 ssq = red4[l];
        #pragma unroll
        for (int i = 1; i < 8; i++) {
            float4 t4 = red4[i * 64 + l];
            ssq.x += t4.x; ssq.y += t4.y; ssq.z += t4.z; ssq.w += t4.w;
        }
        float4 invn;
        invn.x = 1.f / fmaxf(sqrtf(ssq.x), 1e-12f);
        invn.y = 1.f / fmaxf(sqrtf(ssq.y), 1e-12f);
        invn.z = 1.f / fmaxf(sqrtf(ssq.z), 1e-12f);
        invn.w = 1.f / fmaxf(sqrtf(ssq.w), 1e-12f);
        *(float4*)(invs + 4 * l) = invn;
        *(float4*)(inv_norm + (size_t)n * SPIX + s0 + 4 * l) = invn;
    }
    __syncthreads();
    float invp = invs[sl];

    // ---- logits = acc*invp + b ----
    const float* bb = b + khu * 32;
    #pragma unroll
    for (int i = 0; i < 32; i++) acc[i] = fmaf(acc[i], invp, bb[i]);

    // ---- softmax over 64 k (32 local x 2 kh halves) ----
    float m = acc[0];
    #pragma unroll
    for (int i = 1; i < 32; i++) m = fmaxf(m, acc[i]);
    redf[tid] = m;
    __syncthreads();
    m = fmaxf(redf[sl], redf[256 + sl]);
    float ssum = 0.f;
    #pragma unroll
    for (int i = 0; i < 32; i++) { float e = __expf(acc[i] - m); acc[i] = e; ssum += e; }
    __syncthreads();
    redf[tid] = ssum;
    __syncthreads();
    float r = 1.0f / (redf[sl] + redf[256 + sl]);
    #pragma unroll
    for (int i = 0; i < 32; i++) acc[i] *= r;

    // ---- write a: aT[n][s][64] ----
    float4* ap = (float4*)(aT + ((size_t)(n * SPIX + s0 + sl)) * KCL + khu * 32);
    #pragma unroll
    for (int j = 0; j < 8; j++) {
        float4 v = {acc[4*j+0], acc[4*j+1], acc[4*j+2], acc[4*j+3]};
        ap[j] = v;
    }

    // ---- asum partials: reduce over 64 lanes (= 64 pixels) per wave ----
    #pragma unroll
    for (int i = 0; i < 32; i++) {
        float v = acc[i];
        #pragma unroll
        for (int off = 32; off > 0; off >>= 1) v += __shfl_xor(v, off, 64);
        if (l == 0) asum_part[(blk * 8 + wv) * 32 + i] = v;
    }
}

// ---------------- K2: vlad partials (round-5 version, verbatim) -------------
// grid 512 = (n, 16 groups of 256 px), 512 threads = (kh = tid>>8, c = tid&255)
// Per-lane x^ from LDS b32 (pad-33, conflict-free), uniform a-slice via
// batched s_load (dense sequential stream). fp32 VALU roofline -- do not touch.
__global__ __launch_bounds__(512, 4) void k_vlad(const float* __restrict__ x,
                                                 const float* __restrict__ inv_norm,
                                                 const float* __restrict__ aT,
                                                 float* __restrict__ vlad_part) {
    int blk = blockIdx.x;
    int n = blk >> 4, g = blk & 15;
    int tid = threadIdx.x;
    int kh = __builtin_amdgcn_readfirstlane(tid >> 8);   // wave-uniform
    int c = tid & 255;

    __shared__ float xt[256 * 33];   // [c][s32], pad 33: conflict-free per-lane reads

    float acc[32];
    #pragma unroll
    for (int i = 0; i < 32; i++) acc[i] = 0.f;

    int sl = tid & 31;       // staging pixel 0..31
    int cr = tid >> 5;       // staging row 0..15

    for (int t = 0; t < 8; t++) {
        int s0 = g * 256 + t * 32;
        float invp = inv_norm[n * SPIX + s0 + sl];
        __syncthreads();   // previous chunk's reads done before overwrite
        #pragma unroll
        for (int i = 0; i < 16; i++) {
            int cc = cr + i * 16;
            xt[cc * 33 + sl] = x[((size_t)n * CDIM + cc) * SPIX + s0 + sl] * invp;
        }
        __syncthreads();

        const float* ab = aT + ((size_t)(n * SPIX + s0)) * KCL + kh * 32;  // uniform
        for (int ss = 0; ss < 32; ss++) {
            float xn = xt[c * 33 + ss];                       // per-lane, conflict-free
            const float4* ap = (const float4*)(ab + ss * 64); // uniform -> s_load
            #pragma unroll
            for (int q = 0; q < 8; q++) {
                float4 a4 = ap[q];
                acc[4*q+0] = fmaf(a4.x, xn, acc[4*q+0]);
                acc[4*q+1] = fmaf(a4.y, xn, acc[4*q+1]);
                acc[4*q+2] = fmaf(a4.z, xn, acc[4*q+2]);
                acc[4*q+3] = fmaf(a4.w, xn, acc[4*q+3]);
            }
        }
    }
    float* vp = vlad_part + ((size_t)blk * KCL + kh * 32) * CDIM + c;
    #pragma unroll
    for (int i = 0; i < 32; i++) vp[(size_t)i * CDIM] = acc[i];   // coalesced
}

// ---------------- K4: combine partials + centroid subtract + intra-norm ----
// grid 2048 = (n,k), 256 threads (c = tid)
__global__ __launch_bounds__(256) void k_combine(const float* __restrict__ vlad_part,
                                                 const float* __restrict__ asum_part,
                                                 const float* __restrict__ cent,
                                                 float* __restrict__ out,
                                                 float* __restrict__ rs) {
    int blk = blockIdx.x;          // n*64 + k
    int n = blk >> 6, k = blk & 63;
    int c = threadIdx.x;
    float v = 0.f;
    for (int j = 0; j < 16; j++)
        v += vlad_part[(((size_t)(n * 16 + j)) * KCL + k) * CDIM + c];
    float as = 0.f;
    int kh = k >> 5, kj = k & 31;
    for (int j = 0; j < 16; j++)
        for (int q = 0; q < 4; q++)
            as += asum_part[(((n * 16 + j) * 8) + kh * 4 + q) * 32 + kj];
    v = fmaf(-as, cent[k * CDIM + c], v);

    float t = v * v;
    #pragma unroll
    for (int off = 32; off > 0; off >>= 1) t += __shfl_xor(t, off, 64);
    __shared__ float w4[4];
    int lane = threadIdx.x & 63, wid = threadIdx.x >> 6;
    if (lane == 0) w4[wid] = t;
    __syncthreads();
    float ss = w4[0] + w4[1] + w4[2] + w4[3];
    float inv = 1.0f / fmaxf(sqrtf(ss), 1e-12f);
    out[(size_t)blk * CDIM + c] = v * inv;
    if (threadIdx.x == 0) rs[blk] = ss * inv * inv;
}

// ---------------- K5: global L2 normalize per image (in place) --------------
// grid 256 = (n, 8), 256 threads
__global__ __launch_bounds__(256) void k_gnorm(const float* __restrict__ rs,
                                               float* __restrict__ out) {
    int n = blockIdx.x >> 3, j = blockIdx.x & 7;
    float ss = 0.f;
    for (int k = 0; k < KCL; k++) ss += rs[n * KCL + k];
    float g = 1.0f / fmaxf(sqrtf(ss), 1e-12f);
    size_t base = (size_t)n * (KCL * CDIM) + j * 2048 + threadIdx.x;
    for (int i = 0; i < 8; i++) out[base + i * 256] *= g;
}

extern "C" void kernel_launch(void* const* d_in, const int* in_sizes, int n_in,
                              void* d_out, int out_size, void* d_ws, size_t ws_size,
                              hipStream_t stream) {
    const float* x    = (const float*)d_in[0];   // [32][256][64][64]
    const float* w    = (const float*)d_in[1];   // [64][256]
    const float* b    = (const float*)d_in[2];   // [64]
    const float* cent = (const float*)d_in[3];   // [64][256]
    float* out = (float*)d_out;

    float* ws = (float*)d_ws;
    float* wT        = ws;                        // 16384
    float* inv_norm  = wT + 16384;                // 131072
    float* aT        = inv_norm + 131072;         // 32*4096*64 = 8388608
    float* vlad_part = aT + 8388608;              // 512*64*256 = 8388608
    float* asum_part = vlad_part + 8388608;       // 512*8*32 = 131072
    float* rs        = asum_part + 131072;        // 2048

    k_wt<<<64, 256, 0, stream>>>(w, wT);
    k_logits<<<512, 512, 0, stream>>>(x, wT, b, aT, inv_norm, asum_part);
    k_vlad<<<512, 512, 0, stream>>>(x, inv_norm, aT, vlad_part);
    k_combine<<<2048, 256, 0, stream>>>(vlad_part, asum_part, cent, out, rs);
    k_gnorm<<<256, 256, 0, stream>>>(rs, out);
}